// Round 11
// baseline (203.523 us; speedup 1.0000x reference)
//
#include <hip/hip_runtime.h>
#include <hip/hip_fp16.h>

// BlockDiagonalLinear hyperbolic layer. Round 11: occupancy + in-flight K1.
//   K0 wrepack32: W f32 -> bf16 frags wb3[b][kf16][nt8][lane][8] (2 MiB ws)
//   K1: grid 1024 = 16 blocks x 64 rowgroups(128 rows); 256 thr (4 waves),
//       launch_bounds(256,4) -> 16 waves/CU. Wave owns nt={2w,2w+1}.
//       4 tiles x 32 rows; per 4-kf batch: 8 A-loads + 8 B-loads issued
//       together (16 x 16B in flight/wave), then cvt+8 MFMA. Zero LDS,
//       zero barriers. mx' fp16 frag-layout chunk store (contiguous).
//   K2 gamma: reduce 16 ssx + 64 ssp partials -> per-row gamma.
//   K3 apply: read frag chunks, out = gam[row]*fp16, 2x128B segs/instr.

typedef __attribute__((ext_vector_type(8))) short short8;
typedef __attribute__((ext_vector_type(16))) float f32x16;

__device__ __forceinline__ ushort f2bf(float f) {
  uint u = __float_as_uint(f);
  return (ushort)((u + 0x7fffu + ((u >> 16) & 1u)) >> 16);  // RNE
}

__device__ __forceinline__ float gamma_of(float sx, float s2) {
  const float xnorm = sqrtf(sx);
  const float un = fmaxf(xnorm, 1e-5f);
  const float a0 = 0.1f * un;
  const float th = tanhf(fminf(a0, 15.f));
  const float c = th / a0;             // h = c * x
  const float hn = th * (xnorm / a0);  // ||h||
  const float xn = fmaxf(hn, 1e-5f);
  const float sp = sqrtf(s2);          // ||mx'||
  float gt = 0.f;
  if (sp > 0.f) {
    const float s = c * sp;  // ||mx||
    const float xc = fminf(0.1f * xn, 1.f - 1e-5f);
    const float at = 0.5f * logf((1.f + xc) / (1.f - xc));  // artanh
    const float t = (s / xn) * at;
    const float tn = tanhf(fminf(t, 15.f));
    const float alpha = tn / (0.1f * s);  // res_c = alpha * mx
    const float rn = tn * 10.f;           // ||res_c||
    const float nrm = fmaxf(rn, 1e-5f);
    const float proj = (nrm > 9.99f) ? (9.99f / nrm) : 1.f;  // _project
    const float yn = fmaxf(rn * proj, 1e-5f);
    const float yc = fminf(0.1f * yn, 1.f - 1e-5f);
    const float at2 = 0.5f * logf((1.f + yc) / (1.f - yc));
    gt = c * alpha * proj * (at2 / (0.1f * yn));  // logmap0 + fold of c
  }
  return gt;
}

// K0: repack for 32x32x16. frag(b,kf,nt): lane l, j -> W[b][nt*32+(l&31)][kf*16+(l>>5)*8+j]
__global__ __launch_bounds__(256) void wrepack32(const float* __restrict__ w,
                                                 ushort* __restrict__ wb3) {
  int idx = blockIdx.x * 256 + threadIdx.x;  // 131072
  int lane = idx & 63;
  int nt = (idx >> 6) & 7;
  int kf = (idx >> 9) & 15;
  int b = idx >> 13;
  int n = nt * 32 + (lane & 31);
  int k0 = kf * 16 + (lane >> 5) * 8;
  const float* src = w + ((size_t)b << 16) + (size_t)n * 256 + k0;
  float4 v0 = *reinterpret_cast<const float4*>(src);
  float4 v1 = *reinterpret_cast<const float4*>(src + 4);
  uint4 p;
  p.x = (uint)f2bf(v0.x) | ((uint)f2bf(v0.y) << 16);
  p.y = (uint)f2bf(v0.z) | ((uint)f2bf(v0.w) << 16);
  p.z = (uint)f2bf(v1.x) | ((uint)f2bf(v1.y) << 16);
  p.w = (uint)f2bf(v1.z) | ((uint)f2bf(v1.w) << 16);
  reinterpret_cast<uint4*>(wb3)[idx] = p;
}

// K1: grid 1024 = 16 blocks x 64 row-groups (128 rows); 256 thr (4 waves).
__global__ __launch_bounds__(256, 4) void k1_kernel(const float* __restrict__ x,
                                                    const ushort* __restrict__ wb3,
                                                    float* __restrict__ ssxP,
                                                    float* __restrict__ sspP,
                                                    ushort* __restrict__ mxw) {
  const int tid = threadIdx.x;
  const int w = tid >> 6;
  const int l = tid & 63;
  const int lo = l & 31;
  const int hi = l >> 5;
  const int b = blockIdx.x & 15;
  const int rg = blockIdx.x >> 4;  // 0..63
  const ushort* bbase = wb3 + ((size_t)b << 16);

  for (int t = 0; t < 4; ++t) {
    const int rt = rg * 4 + t;  // global row-tile 0..255
    const float* abase = x + ((size_t)rt * 32 + lo) * 4096 + b * 256 + hi * 8;

    f32x16 a0, a1;
#pragma unroll
    for (int r = 0; r < 16; ++r) { a0[r] = 0.f; a1[r] = 0.f; }
    float ssl = 0.f;

    // ---- 4 batches of 4 kf: 8 A-loads + 8 B-loads in flight together ----
#pragma unroll
    for (int bb4 = 0; bb4 < 4; ++bb4) {
      float4 va[8];
      short8 vb[8];
#pragma unroll
      for (int k4 = 0; k4 < 4; ++k4) {
        const int kf = bb4 * 4 + k4;
        va[k4 * 2 + 0] = *reinterpret_cast<const float4*>(abase + kf * 16);
        va[k4 * 2 + 1] = *reinterpret_cast<const float4*>(abase + kf * 16 + 4);
      }
#pragma unroll
      for (int k4 = 0; k4 < 4; ++k4) {
        const int kf = bb4 * 4 + k4;
        vb[k4 * 2 + 0] = *reinterpret_cast<const short8*>(
            bbase + (size_t)(kf * 8 + w * 2 + 0) * 512 + l * 8);
        vb[k4 * 2 + 1] = *reinterpret_cast<const short8*>(
            bbase + (size_t)(kf * 8 + w * 2 + 1) * 512 + l * 8);
      }
      if (w == 0) {
#pragma unroll
        for (int i = 0; i < 8; ++i)
          ssl += va[i].x * va[i].x + va[i].y * va[i].y + va[i].z * va[i].z + va[i].w * va[i].w;
      }
#pragma unroll
      for (int k4 = 0; k4 < 4; ++k4) {
        const float4 v0 = va[k4 * 2], v1 = va[k4 * 2 + 1];
        short8 af;
        af[0] = (short)f2bf(v0.x); af[1] = (short)f2bf(v0.y);
        af[2] = (short)f2bf(v0.z); af[3] = (short)f2bf(v0.w);
        af[4] = (short)f2bf(v1.x); af[5] = (short)f2bf(v1.y);
        af[6] = (short)f2bf(v1.z); af[7] = (short)f2bf(v1.w);
        a0 = __builtin_amdgcn_mfma_f32_32x32x16_bf16(af, vb[k4 * 2 + 0], a0, 0, 0, 0);
        a1 = __builtin_amdgcn_mfma_f32_32x32x16_bf16(af, vb[k4 * 2 + 1], a1, 0, 0, 0);
      }
    }

    // ---- ssx (wave 0; f32-exact): combine hi-halves, hi==0 stores ----
    if (w == 0) {
      ssl += __shfl_xor(ssl, 32, 64);
      if (hi == 0) ssxP[b * 8192 + rt * 32 + lo] = ssl;  // 128B contiguous
    }

    // ---- ssp partials across lo within each half ----
    {
      float s[16];
#pragma unroll
      for (int r = 0; r < 16; ++r) s[r] = a0[r] * a0[r] + a1[r] * a1[r];
#pragma unroll
      for (int m = 1; m < 32; m <<= 1)
#pragma unroll
        for (int r = 0; r < 16; ++r) s[r] += __shfl_xor(s[r], m, 64);
      if (lo == 0) {
#pragma unroll
        for (int r = 0; r < 16; ++r) {
          const int rr = (r & 3) + 8 * (r >> 2) + 4 * hi;
          sspP[(size_t)(b * 4 + w) * 8192 + rt * 32 + rr] = s[r];
        }
      }
    }

    // ---- pack fp16 + fragment-layout chunk store (fully contiguous) ----
    {
      uint wds[16];
#pragma unroll
      for (int j = 0; j < 8; ++j) {
        __half2 h0 = __floats2half2_rn(a0[2 * j], a0[2 * j + 1]);
        __half2 h1 = __floats2half2_rn(a1[2 * j], a1[2 * j + 1]);
        wds[j] = *reinterpret_cast<uint*>(&h0);
        wds[8 + j] = *reinterpret_cast<uint*>(&h1);
      }
      ushort* dst = mxw + (size_t)((b * 256 + rt) * 4 + w) * 2048;
#pragma unroll
      for (int i = 0; i < 4; ++i) {
        uint4 p;
        p.x = wds[i * 4 + 0]; p.y = wds[i * 4 + 1];
        p.z = wds[i * 4 + 2]; p.w = wds[i * 4 + 3];
        *reinterpret_cast<uint4*>(dst + (size_t)(i * 64 + l) * 8) = p;  // 1KB/instr
      }
    }
  }
}

// K2: gamma per row (16 ssx partials, 64 ssp partials).
__global__ __launch_bounds__(256) void gamma_kernel(const float* __restrict__ ssxP,
                                                    const float* __restrict__ sspP,
                                                    float* __restrict__ gam) {
  const int row = blockIdx.x * 256 + threadIdx.x;
  float sx = 0.f, s2 = 0.f;
#pragma unroll
  for (int bb = 0; bb < 16; ++bb) sx += ssxP[bb * 8192 + row];
#pragma unroll
  for (int p = 0; p < 64; ++p) s2 += sspP[(size_t)p * 8192 + row];
  gam[row] = gamma_of(sx, s2);
}

// K3: read frag chunks, scale by gam[row], store to out (2x128B segs/instr).
__global__ __launch_bounds__(256) void k3_kernel(const ushort* __restrict__ mxw,
                                                 const float* __restrict__ gam,
                                                 float* __restrict__ out) {
  const int wt = blockIdx.x * 4 + (threadIdx.x >> 6);  // 0..16383
  const int l = threadIdx.x & 63;
  const int lo = l & 31;
  const int hi = l >> 5;
  const int w = wt & 3;
  const int rt = (wt >> 2) & 255;
  const int b = wt >> 10;
  const ushort* src = mxw + (size_t)wt * 2048;
  uint4 p[4];
#pragma unroll
  for (int i = 0; i < 4; ++i)
    p[i] = *reinterpret_cast<const uint4*>(src + (size_t)(i * 64 + l) * 8);
  const int colbase = b * 256 + w * 64 + lo;  // a0 col; a1 col = +32
  const int rowb = rt * 32 + 4 * hi;
  const uint* pw = reinterpret_cast<const uint*>(p);
#pragma unroll
  for (int j = 0; j < 8; ++j) {
    const int r0 = 2 * j, r1 = 2 * j + 1;
    const int R0 = rowb + (r0 & 3) + 8 * (r0 >> 2);
    const int R1 = rowb + (r1 & 3) + 8 * (r1 >> 2);
    uint w0 = pw[j];
    uint w1 = pw[8 + j];
    float2 f0 = __half22float2(*reinterpret_cast<__half2*>(&w0));
    float2 f1 = __half22float2(*reinterpret_cast<__half2*>(&w1));
    const float g0 = gam[R0], g1 = gam[R1];
    out[(size_t)R0 * 4096 + colbase] = f0.x * g0;
    out[(size_t)R1 * 4096 + colbase] = f0.y * g1;
    out[(size_t)R0 * 4096 + colbase + 32] = f1.x * g0;
    out[(size_t)R1 * 4096 + colbase + 32] = f1.y * g1;
  }
}

extern "C" void kernel_launch(void* const* d_in, const int* in_sizes, int n_in,
                              void* d_out, int out_size, void* d_ws, size_t ws_size,
                              hipStream_t stream) {
  const float* x = (const float*)d_in[0];  // [4,2048,4096] f32
  const float* w = (const float*)d_in[1];  // [16,256,256] f32
  float* out = (float*)d_out;              // [4,2048,4096] f32

  const size_t WB = (size_t)2 << 20;                   // wb3: 2 MiB @ 0
  const size_t SSX_OFF = WB;                           // ssxP: 512 KiB
  const size_t SSP_OFF = WB + ((size_t)512 << 10);     // sspP: 2 MiB (64 x 8192 f32)
  const size_t MXW_OFF = SSP_OFF + ((size_t)2 << 20);  // mxw: 64 MiB (frag layout)
  const size_t NEED = MXW_OFF + (size_t)16 * 8192 * 256 * 2;

  if (ws_size >= NEED) {
    ushort* wb3 = (ushort*)d_ws;
    float* ssxP = (float*)((char*)d_ws + SSX_OFF);
    float* sspP = (float*)((char*)d_ws + SSP_OFF);
    float* gamv = (float*)d_ws;  // overlaps wb3 (dead after K1)
    ushort* mxw = (ushort*)((char*)d_ws + MXW_OFF);
    wrepack32<<<512, 256, 0, stream>>>(w, wb3);
    k1_kernel<<<1024, 256, 0, stream>>>(x, wb3, ssxP, sspP, mxw);
    gamma_kernel<<<32, 256, 0, stream>>>(ssxP, sspP, gamv);  // gamv clobbers wb3 (dead)
    k3_kernel<<<4096, 256, 0, stream>>>(mxw, gamv, out);
  }
}